// Round 1
// baseline (353.788 us; speedup 1.0000x reference)
//
#include <hip/hip_runtime.h>
#include <hip/hip_bf16.h>

// Problem constants
//   x: (2,40,40,40,64) f32, linear_weight: 512 f32, weight: (8,1024) f32
//   out: (2,40,40,40,64) f32 = conv3d(x, K) with sc folded into center tap.
// ws layout: xp bf16 padded (2,44,44,44,64) at offset 0 (21,807,104 B),
//            Kb bf16 [125][8][64][8] at offset 21,807,104 (1,024,000 B).

typedef __bf16 bf16x8 __attribute__((ext_vector_type(8)));
typedef float f32x4 __attribute__((ext_vector_type(4)));

#define XP_BYTES 21807104

// ---------------- pad + cast x -> xp (zero borders, bf16) ----------------
__global__ __launch_bounds__(256) void pad_cast(const float* __restrict__ x,
                                                ushort* __restrict__ xp) {
  int tid = blockIdx.x * 256 + threadIdx.x;      // 0 .. 1,362,944
  int c8 = (tid & 7) * 8;                        // channel chunk of 8
  int v = tid >> 3;                              // voxel id in padded grid
  int zi = v % 44; int t = v / 44;
  int yi = t % 44; t /= 44;
  int xi = t % 44; int n = t / 44;
  int4 st;
  if (xi >= 2 && xi < 42 && yi >= 2 && yi < 42 && zi >= 2 && zi < 42) {
    const float* src = x + ((((size_t)n * 40 + (xi - 2)) * 40 + (yi - 2)) * 40 + (zi - 2)) * 64 + c8;
    float4 f0 = ((const float4*)src)[0];
    float4 f1 = ((const float4*)src)[1];
    union { __hip_bfloat16 h[8]; int4 v4; } u;
    u.h[0] = __float2bfloat16(f0.x); u.h[1] = __float2bfloat16(f0.y);
    u.h[2] = __float2bfloat16(f0.z); u.h[3] = __float2bfloat16(f0.w);
    u.h[4] = __float2bfloat16(f1.x); u.h[5] = __float2bfloat16(f1.y);
    u.h[6] = __float2bfloat16(f1.z); u.h[7] = __float2bfloat16(f1.w);
    st = u.v4;
  } else {
    st = make_int4(0, 0, 0, 0);
  }
  ((int4*)xp)[tid] = st;   // tid*16B == (v*64 + c8)*2B
}

// ---------------- build Kb: analytic kernel, fragment-friendly layout ----------------
// Kb[l][i>>3][o][i&7], i = input channel (row), o = output channel (col).
__global__ __launch_bounds__(256) void build_k(const float* __restrict__ lw,
                                               const float* __restrict__ wt,
                                               ushort* __restrict__ Kb) {
  int l = blockIdx.x;            // 0..124
  int t = threadIdx.x;
  int o = t & 63;
  int ig = t >> 6;               // i group (16 i's each)

  int ix = l / 25; int rem = l - ix * 25; int iy = rem / 5; int iz = rem - iy * 5;
  float cx = (float)(ix - 2), cy = (float)(iy - 2), cz = (float)(iz - 2);
  float r = sqrtf(cx * cx + cy * cy + cz * cz);

  // radial embedding (soft bump basis), matches reference exactly in f32
  float e[8];
  const float step = 2.5f / 9.0f;
  #pragma unroll
  for (int b = 0; b < 8; b++) {
    float diff = (r - (float)(b + 1) * step) / step;
    float den = fmaxf(1.0f - diff * diff, 1e-9f);
    e[b] = (fabsf(diff) < 1.0f) ? 1.14136f * expf(2.0f - 1.0f / den) : 0.0f;
  }
  float inv = (r > 0.0f) ? 1.0f / r : 0.0f;
  const float s3 = 1.7320508075688772f;
  float y1[3] = { s3 * cx * inv, s3 * cy * inv, s3 * cz * inv };
  const float a = 0.17677669529663687f;     // 1/sqrt(2*MUL)
  const float a3 = 0.10206207261596575f;    // a/sqrt(3)

  auto wElem = [&](int c, int u, int w) -> float {
    const float* p = wt + c * 256 + u * 16 + w;
    float s = 0.f;
    #pragma unroll
    for (int b = 0; b < 8; b++) s += e[b] * p[b * 1024];
    return s * (1.0f / 125.0f);
  };

  for (int rr = 0; rr < 16; rr++) {
    int i = ig * 16 + rr;
    float val;
    if (i < 16) {
      if (o < 16) {                       // Rss
        val = a * wElem(0, i, o);
      } else {                            // Rsv
        int om = o - 16; int w = om / 3, m = om - 3 * w;
        val = a * wElem(1, i, w) * y1[m];
      }
    } else {
      int im = i - 16; int u = im / 3, m = im - 3 * u;
      if (o < 16) {                       // Rvs
        val = a3 * wElem(3, u, o) * y1[m];
      } else {                            // Rvv (diagonal in m,n)
        int om = o - 16; int w = om / 3, n = om - 3 * w;
        val = (m == n) ? a * wElem(2, u, w) : 0.0f;
      }
    }
    // fold self-connection into center tap (2,2,2) -> l == 62
    if (l == 62) {
      if (i < 16 && o < 16) {
        val += lw[i * 16 + o] * 0.25f;
      } else if (i >= 16 && o >= 16) {
        int im = i - 16, om = o - 16;
        int u = im / 3, m = im - 3 * u;
        int w = om / 3, n = om - 3 * w;
        if (m == n) val += lw[256 + u * 16 + w] * 0.25f;
      }
    }
    ((__hip_bfloat16*)Kb)[((size_t)(l * 8 + (i >> 3)) * 64 + o) * 8 + (i & 7)] = __float2bfloat16(val);
  }
}

// ---------------- conv: implicit GEMM, M=128/block, N=64, K=8000 ----------------
__global__ __launch_bounds__(256, 4) void conv_mfma(const ushort* __restrict__ xp_,
                                                    const ushort* __restrict__ Kb_,
                                                    float* __restrict__ out) {
  const __bf16* xp = (const __bf16*)xp_;
  __shared__ __bf16 smem[2][4096];   // double-buffered per-tap B slice (8 KB each... 4096 bf16 = 8KB/buf)

  const int tid = threadIdx.x;
  const int lane = tid & 63;
  const int wv = tid >> 6;         // wave id 0..3
  const int g = lane >> 4;         // k-group within fragment
  const int ol = lane & 15;        // output col within 16-tile
  const int pw = blockIdx.x * 128 + wv * 32;   // wave's first position row

  // per-lane A-row base offsets into xp for mt=0,1 (row = lane&15)
  size_t baseOff[2];
  #pragma unroll
  for (int mt = 0; mt < 2; mt++) {
    int p = pw + mt * 16 + (lane & 15);
    int z = p % 40; int q = p / 40;
    int y = q % 40; q /= 40;
    int x = q % 40; int n = q / 40;
    baseOff[mt] = ((((size_t)n * 44 + x) * 44 + y) * 44 + z) * 64 + g * 8;
  }

  f32x4 acc[2][4] = {};  // [mt][nt], zero-init

  // B staging: per tap 4096 bf16 = 512 int4; this thread's 2 chunks
  const int4* kbase = (const int4*)Kb_;
  const int sidx = wv * 128 + lane;
  int4 stg0, stg1;

  // prologue: stage tap 0 into buf 0
  stg0 = kbase[sidx];
  stg1 = kbase[sidx + 64];
  {
    int4* d = (int4*)&smem[0][0];
    d[sidx] = stg0; d[sidx + 64] = stg1;
  }
  __syncthreads();

  for (int l = 0; l < 125; l++) {
    const int cur = l & 1;
    // issue next tap's global loads early (latency hidden under MFMA)
    if (l < 124) {
      int b = (l + 1) * 512 + sidx;
      stg0 = kbase[b];
      stg1 = kbase[b + 64];
    }
    // tap offset into xp
    int dx = l / 25; int rem = l - dx * 25; int dy = rem / 5; int dz = rem - dy * 5;
    size_t tapOff = ((size_t)(dx * 44 + dy) * 44 + dz) * 64;

    const __bf16* sb = &smem[cur][0];
    #pragma unroll
    for (int kc = 0; kc < 2; kc++) {
      bf16x8 a0 = *(const bf16x8*)(xp + baseOff[0] + tapOff + kc * 32);
      bf16x8 a1 = *(const bf16x8*)(xp + baseOff[1] + tapOff + kc * 32);
      #pragma unroll
      for (int nt = 0; nt < 4; nt++) {
        bf16x8 bF = *(const bf16x8*)(sb + ((size_t)((kc * 4 + g) * 64 + nt * 16 + ol)) * 8);
        acc[0][nt] = __builtin_amdgcn_mfma_f32_16x16x32_bf16(a0, bF, acc[0][nt], 0, 0, 0);
        acc[1][nt] = __builtin_amdgcn_mfma_f32_16x16x32_bf16(a1, bF, acc[1][nt], 0, 0, 0);
      }
    }
    // write-late: store next tap's slice into the other buffer
    if (l < 124) {
      int4* d = (int4*)&smem[cur ^ 1][0];
      d[sidx] = stg0; d[sidx + 64] = stg1;
    }
    __syncthreads();
  }

  // epilogue: C/D layout col=lane&15, row=(lane>>4)*4+j
  #pragma unroll
  for (int mt = 0; mt < 2; mt++) {
    #pragma unroll
    for (int nt = 0; nt < 4; nt++) {
      #pragma unroll
      for (int j = 0; j < 4; j++) {
        int p = pw + mt * 16 + g * 4 + j;
        out[(size_t)p * 64 + nt * 16 + ol] = acc[mt][nt][j];
      }
    }
  }
}

extern "C" void kernel_launch(void* const* d_in, const int* in_sizes, int n_in,
                              void* d_out, int out_size, void* d_ws, size_t ws_size,
                              hipStream_t stream) {
  const float* x  = (const float*)d_in[0];
  const float* lw = (const float*)d_in[1];
  const float* wt = (const float*)d_in[2];
  float* out = (float*)d_out;
  ushort* xp = (ushort*)d_ws;
  ushort* Kb = (ushort*)((char*)d_ws + XP_BYTES);

  pad_cast<<<5324, 256, 0, stream>>>(x, xp);
  build_k<<<125, 256, 0, stream>>>(lw, wt, Kb);
  conv_mfma<<<1000, 256, 0, stream>>>(xp, Kb, out);
}